// Round 1
// baseline (595.920 us; speedup 1.0000x reference)
//
#include <hip/hip_runtime.h>
#include <stdint.h>

// GraphConvolution: out[0:8192]    = deg[i]     *(adj  @ (v@Wv)) + bias
//                   out[8192:16k]  = deg[8192+j]*(adjT @ (u@Wu)) + bias
// R4: two-pass sequential-stream design. k_top = row GEMM fused with bf16
// transpose staging of adj into 16-col panels (ws); k_bot = pure bf16 panel
// GEMM (no f2b, no LDS, no fences in K-loop). All HBM streams sequential.
// HBM budget: 256R+128W (k_top) + 128R (k_bot) = 512 MiB ~ 80 us floor.

#define HID 64
#define IN_DIM 128
#define NROWS 8192
#define NCLS 5

typedef float f32x4 __attribute__((ext_vector_type(4)));
typedef short s16x8 __attribute__((ext_vector_type(8)));
typedef unsigned short u16;

static __device__ __forceinline__ short f2b(float x) {  // RNE fp32->bf16
    unsigned u = __builtin_bit_cast(unsigned, x);
    return (short)((u + 0x7FFFu + ((u >> 16) & 1u)) >> 16);
}

// ---------------------------------------------------------------------------
// k_prep: W = sum_{c<=r} weight[c]; s = X @ W; store transposed bf16 [h][row]
// grid (128, 2): y=0 -> suT (from u), y=1 -> svT (from v). block 256.
// ---------------------------------------------------------------------------
__global__ __launch_bounds__(256, 2) void k_prep(
    const float* __restrict__ u, const float* __restrict__ v,
    const float* __restrict__ uw, const float* __restrict__ vw,
    const int* __restrict__ rp, u16* __restrict__ ws)
{
    __shared__ float W[IN_DIM * HID];
    __shared__ float X[64 * 129];

    const int y = blockIdx.y;
    const float* __restrict__ src  = y ? v  : u;
    const float* __restrict__ wsrc = y ? vw : uw;
    u16* __restrict__ dstT = ws + (size_t)y * (HID * NROWS);
    const int i0 = blockIdx.x * 64;
    const int t = threadIdx.x;
    int r = *rp; if (r > NCLS - 1) r = NCLS - 1; if (r < 0) r = 0;

    for (int idx = t; idx < IN_DIM * HID; idx += 256) {
        float s = 0.f;
        for (int c = 0; c <= r; ++c) s += wsrc[c * (IN_DIM * HID) + idx];
        W[idx] = s;
    }
    #pragma unroll
    for (int qq = 0; qq < 8; ++qq) {       // 64 rows x 32 float4 = 2048
        int idx = t + qq * 256;
        int row = idx >> 5, c4 = idx & 31;
        f32x4 val = *(const f32x4*)&src[(size_t)(i0 + row) * IN_DIM + c4 * 4];
        float* d = &X[row * 129 + c4 * 4];
        d[0] = val[0]; d[1] = val[1]; d[2] = val[2]; d[3] = val[3];
    }
    __syncthreads();

    const int i = t & 63, h0 = (t >> 6) * 16;
    float acc[16];
    #pragma unroll
    for (int k = 0; k < 16; ++k) acc[k] = 0.f;
    for (int c = 0; c < IN_DIM; ++c) {
        float uv = X[i * 129 + c];
        const f32x4* wr = (const f32x4*)&W[c * HID + h0];
        f32x4 w0 = wr[0], w1 = wr[1], w2 = wr[2], w3 = wr[3];
        acc[0]  += uv * w0[0]; acc[1]  += uv * w0[1];
        acc[2]  += uv * w0[2]; acc[3]  += uv * w0[3];
        acc[4]  += uv * w1[0]; acc[5]  += uv * w1[1];
        acc[6]  += uv * w1[2]; acc[7]  += uv * w1[3];
        acc[8]  += uv * w2[0]; acc[9]  += uv * w2[1];
        acc[10] += uv * w2[2]; acc[11] += uv * w2[3];
        acc[12] += uv * w3[0]; acc[13] += uv * w3[1];
        acc[14] += uv * w3[2]; acc[15] += uv * w3[3];
    }
    #pragma unroll
    for (int hh = 0; hh < 16; ++hh)
        dstT[(size_t)(h0 + hh) * NROWS + i0 + i] = (u16)f2b(acc[hh]);
}

// ---------------------------------------------------------------------------
// k_top: 512 blocks, 16-row strips, 4 waves = K-quarters (2048 each).
// Per tau (64 cols): MFMA top-GEMM from register-loaded adj rows, AND
// bf16-transpose-store of the same tile into 16-col panels at
// wt[Jc][ib=bx][jj][ii]  (Jc = col/16, ii = row%16), coalesced 512B bursts.
// LDS tile stores MFMA A-frags (b128, XOR slot swizzle: 2-way = free);
// reads are per-(row,col) u16 (paired-broadcast = free). Next-tau adj loads
// are issued BEFORE the lgkm fence so HBM latency hides under the tau body.
// ---------------------------------------------------------------------------
__global__ __launch_bounds__(256, 2) void k_top(
    const float* __restrict__ adj, const float* __restrict__ degree,
    const float* __restrict__ bias, const u16* __restrict__ ws,
    u16* __restrict__ wt, float* __restrict__ out)
{
    __shared__ u16  Tt[4][16 * 64];   // per-wave bf16 tile, slot-swizzled
    __shared__ float S[4][16 * 64];   // per-wave partials for reduce

    const int bx = blockIdx.x;
    const int t = threadIdx.x;
    const int w = t >> 6, l = t & 63;
    const int q = l >> 4, l15 = l & 15;
    const int m0 = bx * 16;
    const int kbase = w * 2048;
    const u16* __restrict__ BT = ws + (size_t)HID * NROWS;   // svT
    const float* __restrict__ ap0 = adj + (size_t)(m0 + l15) * NROWS + q * 8;
    u16* __restrict__ Tw = Tt[w];

    f32x4 acc[4];
    #pragma unroll
    for (int nn = 0; nn < 4; ++nn) acc[nn] = (f32x4){0.f, 0.f, 0.f, 0.f};

    // prologue: load tau=0 tile rows into regs
    f32x4 c00 = *(const f32x4*)(ap0 + kbase);
    f32x4 c01 = *(const f32x4*)(ap0 + kbase + 4);
    f32x4 c10 = *(const f32x4*)(ap0 + kbase + 32);
    f32x4 c11 = *(const f32x4*)(ap0 + kbase + 36);

    for (int tau = 0; tau < 32; ++tau) {
        const int k0c = kbase + tau * 64;
        const int knx = kbase + ((tau + 1) & 31) * 64;   // wraps; tail reload harmless
        // prefetch next tau BEFORE any fence so loads stay in flight
        f32x4 n00 = *(const f32x4*)(ap0 + knx);
        f32x4 n01 = *(const f32x4*)(ap0 + knx + 4);
        f32x4 n10 = *(const f32x4*)(ap0 + knx + 32);
        f32x4 n11 = *(const f32x4*)(ap0 + knx + 36);

        // ---- kh = 0: cols k0c + q*8 + 0..7 ----
        s16x8 af0;
        af0[0]=f2b(c00[0]); af0[1]=f2b(c00[1]); af0[2]=f2b(c00[2]); af0[3]=f2b(c00[3]);
        af0[4]=f2b(c01[0]); af0[5]=f2b(c01[1]); af0[6]=f2b(c01[2]); af0[7]=f2b(c01[3]);
        *(s16x8*)&Tw[l15 * 64 + ((q ^ (l15 & 7)) * 8)] = af0;   // slot s=q
        {
            s16x8 bf[4];
            #pragma unroll
            for (int nn = 0; nn < 4; ++nn)
                bf[nn] = *(const s16x8*)(BT + (size_t)(nn * 16 + l15) * NROWS + k0c + q * 8);
            #pragma unroll
            for (int nn = 0; nn < 4; ++nn)
                acc[nn] = __builtin_amdgcn_mfma_f32_16x16x32_bf16(af0, bf[nn], acc[nn], 0, 0, 0);
        }
        // ---- kh = 1: cols k0c + 32 + q*8 + 0..7 ----
        s16x8 af1;
        af1[0]=f2b(c10[0]); af1[1]=f2b(c10[1]); af1[2]=f2b(c10[2]); af1[3]=f2b(c10[3]);
        af1[4]=f2b(c11[0]); af1[5]=f2b(c11[1]); af1[6]=f2b(c11[2]); af1[7]=f2b(c11[3]);
        *(s16x8*)&Tw[l15 * 64 + (((4 + q) ^ (l15 & 7)) * 8)] = af1;  // slot s=4+q
        {
            s16x8 bf[4];
            #pragma unroll
            for (int nn = 0; nn < 4; ++nn)
                bf[nn] = *(const s16x8*)(BT + (size_t)(nn * 16 + l15) * NROWS + k0c + 32 + q * 8);
            #pragma unroll
            for (int nn = 0; nn < 4; ++nn)
                acc[nn] = __builtin_amdgcn_mfma_f32_16x16x32_bf16(af1, bf[nn], acc[nn], 0, 0, 0);
        }

        // cross-lane LDS hazard: all 64 lanes' writes must land before reads
        asm volatile("s_waitcnt lgkmcnt(0)" ::: "memory");

        // read column c=l of the tile: element (row ii, col l) lives at
        // ii*64 + ((l>>3)^(ii&7))*8 + (l&7)
        s16x8 p0, p1;
        #pragma unroll
        for (int ii = 0; ii < 8; ++ii)
            p0[ii] = (short)Tw[ii * 64 + (((l >> 3) ^ ii) & 7) * 8 + (l & 7)];
        #pragma unroll
        for (int ii = 0; ii < 8; ++ii)
            p1[ii] = (short)Tw[(ii + 8) * 64 + (((l >> 3) ^ ii) & 7) * 8 + (l & 7)];

        // panel store: global col = k0c + l -> Jc=(k0c>>4)+(l>>4), jj=l&15
        u16* dst = wt + (size_t)((k0c >> 4) + (l >> 4)) * (NROWS * 16)
                      + (size_t)bx * 256 + (size_t)(l & 15) * 16;
        *(s16x8*)dst       = p0;   // ii 0..7
        *(s16x8*)(dst + 8) = p1;   // ii 8..15

        asm volatile("" ::: "memory");   // keep next tau's LDS writes after reads
        c00 = n00; c01 = n01; c10 = n10; c11 = n11;
    }

    // partials -> own LDS region (C/D: col n = l15, row m = q*4+rg; m89)
    asm volatile("" ::: "memory");
    {
        float* __restrict__ P = S[w];
        #pragma unroll
        for (int nn = 0; nn < 4; ++nn)
            #pragma unroll
            for (int rg = 0; rg < 4; ++rg)
                P[(q * 4 + rg) * 64 + nn * 16 + l15] = acc[nn][rg];
    }
    __syncthreads();

    // reduce 4 K-quarters, scale + bias, coalesced f32x4 stores (rows m0..m0+15)
    const int e0 = t * 4;               // 256 thr x 4 = 1024 = 16x64
    const int m = e0 >> 6, n = e0 & 63;
    f32x4 s = (f32x4){0.f, 0.f, 0.f, 0.f};
    #pragma unroll
    for (int ww = 0; ww < 4; ++ww) s += *(const f32x4*)&S[ww][e0];
    const int grow = m0 + m;
    const float d = degree[grow];
    f32x4 b = *(const f32x4*)&bias[n];
    *(f32x4*)&out[(size_t)grow * HID + n] = d * s + b;
}

// ---------------------------------------------------------------------------
// k_bot: 512 blocks, 16-col strips; wave = K-quarter over i. Pure streaming
// GEMM: A = bf16 adjT panel (sequential 1 KiB/instr loads), B = suT. No f2b,
// no LDS, no fences in the K-loop -> compiler pipelines freely.
// ---------------------------------------------------------------------------
__global__ __launch_bounds__(256, 2) void k_bot(
    const float* __restrict__ degree, const float* __restrict__ bias,
    const u16* __restrict__ ws, const u16* __restrict__ wt,
    float* __restrict__ out)
{
    __shared__ float S[4][16 * 64];

    const int bx = blockIdx.x;
    const int t = threadIdx.x;
    const int w = t >> 6, l = t & 63;
    const int q = l >> 4, l15 = l & 15;
    const int m0 = bx * 16;
    const int kbase = w * 2048;
    const u16* __restrict__ BT = ws;                         // suT
    const u16* __restrict__ PB = wt + (size_t)bx * (NROWS * 16)
                                    + (size_t)l15 * 16 + (size_t)(q & 1) * 8;

    f32x4 acc[4];
    #pragma unroll
    for (int nn = 0; nn < 4; ++nn) acc[nn] = (f32x4){0.f, 0.f, 0.f, 0.f};

    for (int tau = 0; tau < 32; ++tau) {
        const int i0 = kbase + tau * 64;
        const int ib0 = (i0 >> 4) + (q >> 1);
        // kh = 0: i = i0 + q*8 + 0..7  == ib0*16 + (q&1)*8 + e
        {
            s16x8 af = *(const s16x8*)(PB + (size_t)ib0 * 256);
            s16x8 bf[4];
            #pragma unroll
            for (int nn = 0; nn < 4; ++nn)
                bf[nn] = *(const s16x8*)(BT + (size_t)(nn * 16 + l15) * NROWS + i0 + q * 8);
            #pragma unroll
            for (int nn = 0; nn < 4; ++nn)
                acc[nn] = __builtin_amdgcn_mfma_f32_16x16x32_bf16(af, bf[nn], acc[nn], 0, 0, 0);
        }
        // kh = 1: i = i0 + 32 + q*8 + 0..7
        {
            s16x8 af = *(const s16x8*)(PB + (size_t)(ib0 + 2) * 256);
            s16x8 bf[4];
            #pragma unroll
            for (int nn = 0; nn < 4; ++nn)
                bf[nn] = *(const s16x8*)(BT + (size_t)(nn * 16 + l15) * NROWS + i0 + 32 + q * 8);
            #pragma unroll
            for (int nn = 0; nn < 4; ++nn)
                acc[nn] = __builtin_amdgcn_mfma_f32_16x16x32_bf16(af, bf[nn], acc[nn], 0, 0, 0);
        }
    }

    asm volatile("" ::: "memory");
    {
        float* __restrict__ P = S[w];
        #pragma unroll
        for (int nn = 0; nn < 4; ++nn)
            #pragma unroll
            for (int rg = 0; rg < 4; ++rg)
                P[(q * 4 + rg) * 64 + nn * 16 + l15] = acc[nn][rg];
    }
    __syncthreads();

    const int e0 = t * 4;
    const int m = e0 >> 6, n = e0 & 63;
    f32x4 s = (f32x4){0.f, 0.f, 0.f, 0.f};
    #pragma unroll
    for (int ww = 0; ww < 4; ++ww) s += *(const f32x4*)&S[ww][e0];
    const int grow = NROWS + m0 + m;
    const float d = degree[grow];
    f32x4 b = *(const f32x4*)&bias[n];
    *(f32x4*)&out[(size_t)grow * HID + n] = d * s + b;
}

extern "C" void kernel_launch(void* const* d_in, const int* in_sizes, int n_in,
                              void* d_out, int out_size, void* d_ws, size_t ws_size,
                              hipStream_t stream) {
    (void)in_sizes; (void)n_in; (void)out_size; (void)ws_size;
    const float* u      = (const float*)d_in[0];
    const float* v      = (const float*)d_in[1];
    const float* adj    = (const float*)d_in[2];
    const float* degree = (const float*)d_in[3];
    const float* uw     = (const float*)d_in[4];
    const float* vw     = (const float*)d_in[5];
    const float* bias   = (const float*)d_in[6];
    const int*   rp     = (const int*)d_in[7];
    u16*   ws  = (u16*)d_ws;            // [0,1MB): suT bf16; [1MB,2MB): svT bf16
    u16*   wt  = ws + 1048576;          // [2MB, 2MB+128MB): bf16 adjT panels
    float* out = (float*)d_out;

    k_prep<<<dim3(128, 2), 256, 0, stream>>>(u, v, uw, vw, rp, ws);
    k_top <<<dim3(512),    256, 0, stream>>>(adj, degree, bias, ws, wt, out);
    k_bot <<<dim3(512),    256, 0, stream>>>(degree, bias, ws, wt, out);
}

// Round 2
// 467.365 us; speedup vs baseline: 1.2751x; 1.2751x over previous
//
#include <hip/hip_runtime.h>
#include <stdint.h>

// GraphConvolution: out[0:8192]    = deg[i]     *(adj  @ (v@Wv)) + bias
//                   out[8192:16k]  = deg[8192+j]*(adjT @ (u@Wu)) + bias
// adj is 256 MiB fp32 -> memory-bound; floor ~41us(dedup)/81us(no dedup).
// R3: barrier-free K-loops; waves are independent 4-way K-splits;
// mode0 register-direct, mode1 per-wave LDS transpose (stride-33, fenced).
// R5: su/sv stored in MFMA B-FRAGMENT-PACKED layout pack[kb][nb][lane][e]
// so each bf load is one contiguous 1KB wave-load (was: 64-line scatter,
// ~4GB L2 traffic ~ 120us -- the real R3 bottleneck, not the adj stream).

#define HID 64
#define IN_DIM 128
#define NROWS 8192
#define NCLS 5

typedef float f32x4 __attribute__((ext_vector_type(4)));
typedef short s16x8 __attribute__((ext_vector_type(8)));
typedef unsigned short u16;

// packed side size: 256 kb * 4 nb * 64 lane * 8 e = 524288 u16 = 1 MiB
#define PACK_SIDE 524288

static __device__ __forceinline__ short f2b(float x) {  // RNE fp32->bf16
    unsigned u = __builtin_bit_cast(unsigned, x);
    return (short)((u + 0x7FFFu + ((u >> 16) & 1u)) >> 16);
}

// ---------------------------------------------------------------------------
// k_prep: W = sum_{c<=r} weight[c]; s = X @ W; store B-fragment-packed bf16:
// pack[kb][nb][lane][e] = s[row = kb*32 + (lane>>4)*8 + e][h = nb*16 + (lane&15)]
// grid (128, 2): y=0 -> pu (from u), y=1 -> pv (from v). block 256.
// ---------------------------------------------------------------------------
__global__ __launch_bounds__(256, 2) void k_prep(
    const float* __restrict__ u, const float* __restrict__ v,
    const float* __restrict__ uw, const float* __restrict__ vw,
    const int* __restrict__ rp, u16* __restrict__ ws)
{
    __shared__ float W[IN_DIM * HID];
    __shared__ float X[64 * 129];

    const int y = blockIdx.y;
    const float* __restrict__ src  = y ? v  : u;
    const float* __restrict__ wsrc = y ? vw : uw;
    u16* __restrict__ dstP = ws + (size_t)y * PACK_SIDE;
    const int i0 = blockIdx.x * 64;
    const int t = threadIdx.x;
    int r = *rp; if (r > NCLS - 1) r = NCLS - 1; if (r < 0) r = 0;

    for (int idx = t; idx < IN_DIM * HID; idx += 256) {
        float s = 0.f;
        for (int c = 0; c <= r; ++c) s += wsrc[c * (IN_DIM * HID) + idx];
        W[idx] = s;
    }
    #pragma unroll
    for (int qq = 0; qq < 8; ++qq) {       // 64 rows x 32 float4 = 2048
        int idx = t + qq * 256;
        int row = idx >> 5, c4 = idx & 31;
        f32x4 val = *(const f32x4*)&src[(size_t)(i0 + row) * IN_DIM + c4 * 4];
        float* d = &X[row * 129 + c4 * 4];
        d[0] = val[0]; d[1] = val[1]; d[2] = val[2]; d[3] = val[3];
    }
    __syncthreads();

    const int i = t & 63, h0 = (t >> 6) * 16;
    float acc[16];
    #pragma unroll
    for (int k = 0; k < 16; ++k) acc[k] = 0.f;
    for (int c = 0; c < IN_DIM; ++c) {
        float uv = X[i * 129 + c];
        const f32x4* wr = (const f32x4*)&W[c * HID + h0];
        f32x4 w0 = wr[0], w1 = wr[1], w2 = wr[2], w3 = wr[3];
        acc[0]  += uv * w0[0]; acc[1]  += uv * w0[1];
        acc[2]  += uv * w0[2]; acc[3]  += uv * w0[3];
        acc[4]  += uv * w1[0]; acc[5]  += uv * w1[1];
        acc[6]  += uv * w1[2]; acc[7]  += uv * w1[3];
        acc[8]  += uv * w2[0]; acc[9]  += uv * w2[1];
        acc[10] += uv * w2[2]; acc[11] += uv * w2[3];
        acc[12] += uv * w3[0]; acc[13] += uv * w3[1];
        acc[14] += uv * w3[2]; acc[15] += uv * w3[3];
    }
    // packed store: row iL = i0+i fixed per thread; h = h0+hh, h>>4 = h0>>4
    const int iL = i0 + i;
    u16* __restrict__ dp = dstP
        + (((size_t)(iL >> 5) * 4 + (h0 >> 4)) << 9)   // (kb*4 + nb) * 512
        + ((iL >> 3) & 3) * 128                        // (lane>>4) * 16 * 8
        + (iL & 7);                                    // e
    #pragma unroll
    for (int hh = 0; hh < 16; ++hh)
        dp[hh * 8] = (u16)f2b(acc[hh]);                // (lane&15) * 8 step
}

// ---------------------------------------------------------------------------
// k_main: grid (256, 2), block 256 = 4 waves. Block bx = one 32-wide strip
// (rows for mode0, cols for mode1); wave w = K-quarter [w*2048,(w+1)*2048).
// No barriers in the K-loop. Diagonal chunk order keeps the transpose
// partners' adj reads temporally aligned for L2/L3 dedup (tau* = b-a mod 32).
// B-operand from packed layout: 1KB contiguous wave-loads (R5).
// End: LDS reduce of 4 partials, scale by degree, + bias, store.
// ---------------------------------------------------------------------------
__global__ __launch_bounds__(256, 2) void k_main(
    const float* __restrict__ adj, const float* __restrict__ degree,
    const float* __restrict__ bias, const u16* __restrict__ ws,
    float* __restrict__ out)
{
    __shared__ float S[4][64 * 33];   // per-wave: transpose tile / partials

    const int mode = blockIdx.y;
    const int bx = blockIdx.x;
    const int t = threadIdx.x;
    const int w = t >> 6, l = t & 63;
    const int q = l >> 4, l15 = l & 15;
    const int m0 = bx * 32;
    const unsigned a = (unsigned)(bx >> 1);        // 64-wide chunk index
    const int kbase = w * 2048;
    // mode0 (top) consumes sv -> pv at PACK_SIDE; mode1 (bot) consumes su -> pu
    const u16* __restrict__ BP = ws + (mode == 0 ? (size_t)PACK_SIDE : 0);
    const u16* __restrict__ BPl = BP + (size_t)l * 8;  // lane-fixed sub-base

    f32x4 acc[2][4];
    #pragma unroll
    for (int i = 0; i < 2; ++i)
        #pragma unroll
        for (int j = 0; j < 4; ++j) acc[i][j] = (f32x4){0.f, 0.f, 0.f, 0.f};

    if (mode == 0) {
        // ---- top: C[m=row][n=h] = adj[row][:] . sv[:][h], reg-direct ----
        const float* __restrict__ ap0 = adj + (size_t)(m0 + l15) * NROWS;
        const float* __restrict__ ap1 = ap0 + (size_t)16 * NROWS;
        for (int tau = 0; tau < 32; ++tau) {
            const int k0 = kbase + (int)(((a + tau) & 31u) << 6);
            #pragma unroll
            for (int kh = 0; kh < 2; ++kh) {
                const int k = k0 + kh * 32 + q * 8;
                const int kb = (k0 >> 5) + kh;
                f32x4 a00 = *(const f32x4*)(ap0 + k);
                f32x4 a01 = *(const f32x4*)(ap0 + k + 4);
                f32x4 a10 = *(const f32x4*)(ap1 + k);
                f32x4 a11 = *(const f32x4*)(ap1 + k + 4);
                s16x8 bf[4];
                #pragma unroll
                for (int nn = 0; nn < 4; ++nn)
                    bf[nn] = *(const s16x8*)(BPl + ((size_t)(kb * 4 + nn) << 9));
                s16x8 af0, af1;
                af0[0]=f2b(a00[0]); af0[1]=f2b(a00[1]); af0[2]=f2b(a00[2]); af0[3]=f2b(a00[3]);
                af0[4]=f2b(a01[0]); af0[5]=f2b(a01[1]); af0[6]=f2b(a01[2]); af0[7]=f2b(a01[3]);
                af1[0]=f2b(a10[0]); af1[1]=f2b(a10[1]); af1[2]=f2b(a10[2]); af1[3]=f2b(a10[3]);
                af1[4]=f2b(a11[0]); af1[5]=f2b(a11[1]); af1[6]=f2b(a11[2]); af1[7]=f2b(a11[3]);
                #pragma unroll
                for (int nn = 0; nn < 4; ++nn) {
                    acc[0][nn] = __builtin_amdgcn_mfma_f32_16x16x32_bf16(af0, bf[nn], acc[0][nn], 0, 0, 0);
                    acc[1][nn] = __builtin_amdgcn_mfma_f32_16x16x32_bf16(af1, bf[nn], acc[1][nn], 0, 0, 0);
                }
            }
        }
    } else {
        // ---- bot: C[m=col j][n=h] = sum_i adj[i][j]*su[i][h]; per-wave
        // LDS transpose tile adj[i0..i0+64][j0..j0+32], stride 33 ----
        float* __restrict__ T = S[w];
        const int wr_r = l >> 3;            // row within 8-row group
        const int wr_c = (l & 7) * 4;       // col within 32
        const float* __restrict__ cb = adj + m0 + wr_c;
        for (int tau = 0; tau < 32; ++tau) {
            const int i0 = kbase + (int)(((a - tau) & 31u) << 6);
            f32x4 tr[8];
            #pragma unroll
            for (int c = 0; c < 8; ++c)
                tr[c] = *(const f32x4*)(cb + (size_t)(i0 + c * 8 + wr_r) * NROWS);
            #pragma unroll
            for (int c = 0; c < 8; ++c) {
                float* d = &T[(c * 8 + wr_r) * 33 + wr_c];
                d[0] = tr[c][0]; d[1] = tr[c][1]; d[2] = tr[c][2]; d[3] = tr[c][3];
            }
            asm volatile("s_waitcnt lgkmcnt(0)" ::: "memory");  // in-wave fence
            #pragma unroll
            for (int kh = 0; kh < 2; ++kh) {
                const int kb = (i0 >> 5) + kh;
                s16x8 bf[4];
                #pragma unroll
                for (int nn = 0; nn < 4; ++nn)
                    bf[nn] = *(const s16x8*)(BPl + ((size_t)(kb * 4 + nn) << 9));
                s16x8 af[2];
                #pragma unroll
                for (int mt = 0; mt < 2; ++mt) {
                    const int j = mt * 16 + l15;
                    #pragma unroll
                    for (int tt = 0; tt < 8; ++tt)
                        af[mt][tt] = f2b(T[(kh * 32 + q * 8 + tt) * 33 + j]);
                }
                #pragma unroll
                for (int nn = 0; nn < 4; ++nn) {
                    acc[0][nn] = __builtin_amdgcn_mfma_f32_16x16x32_bf16(af[0], bf[nn], acc[0][nn], 0, 0, 0);
                    acc[1][nn] = __builtin_amdgcn_mfma_f32_16x16x32_bf16(af[1], bf[nn], acc[1][nn], 0, 0, 0);
                }
            }
            asm volatile("" ::: "memory");  // keep next tau's writes after reads
        }
    }

    // partials -> own LDS region (C/D layout: col=l15, row=q*4+reg; m89)
    asm volatile("" ::: "memory");
    {
        float* __restrict__ P = S[w];
        #pragma unroll
        for (int mt = 0; mt < 2; ++mt)
            #pragma unroll
            for (int nn = 0; nn < 4; ++nn)
                #pragma unroll
                for (int rg = 0; rg < 4; ++rg)
                    P[(mt * 16 + q * 4 + rg) * 64 + nn * 16 + l15] = acc[mt][nn][rg];
    }
    __syncthreads();

    // reduce 4 K-splits, scale + bias, coalesced f32x4 stores
    const int e0 = t * 8;
    const int m = e0 >> 6, n = e0 & 63;
    f32x4 s0 = (f32x4){0.f,0.f,0.f,0.f}, s1 = s0;
    #pragma unroll
    for (int ww = 0; ww < 4; ++ww) {
        s0 += *(const f32x4*)&S[ww][e0];
        s1 += *(const f32x4*)&S[ww][e0 + 4];
    }
    const int grow = (mode ? NROWS : 0) + m0 + m;
    const float d = degree[grow];
    f32x4 b0 = *(const f32x4*)&bias[n];
    f32x4 b1 = *(const f32x4*)&bias[n + 4];
    f32x4 o0 = d * s0 + b0;
    f32x4 o1 = d * s1 + b1;
    *(f32x4*)&out[(size_t)grow * HID + n]     = o0;
    *(f32x4*)&out[(size_t)grow * HID + n + 4] = o1;
}

extern "C" void kernel_launch(void* const* d_in, const int* in_sizes, int n_in,
                              void* d_out, int out_size, void* d_ws, size_t ws_size,
                              hipStream_t stream) {
    (void)in_sizes; (void)n_in; (void)out_size; (void)ws_size;
    const float* u      = (const float*)d_in[0];
    const float* v      = (const float*)d_in[1];
    const float* adj    = (const float*)d_in[2];
    const float* degree = (const float*)d_in[3];
    const float* uw     = (const float*)d_in[4];
    const float* vw     = (const float*)d_in[5];
    const float* bias   = (const float*)d_in[6];
    const int*   rp     = (const int*)d_in[7];
    u16*   ws  = (u16*)d_ws;     // [0,1MB): pu packed; [1MB,2MB): pv packed
    float* out = (float*)d_out;

    k_prep<<<dim3(128, 2), 256, 0, stream>>>(u, v, uw, vw, rp, ws);
    k_main<<<dim3(256, 2), 256, 0, stream>>>(adj, degree, bias, ws, out);
}